// Round 3
// baseline (444.110 us; speedup 1.0000x reference)
//
#include <hip/hip_runtime.h>

// DynamicExpertGating: routed MoE on MI355X (gfx950)
//   tokens T=8192 (B4 x S2048), H=1024, D=1024, E=8, top-2
// R3: both GEMMs restructured to LDS-free direct-to-register MFMA loops
// (AITER-style MFMA<->global_load interleave, zero barriers in K-loop).
// R2's m97-style LDS staging was 70% stall here: only 4 blocks/CU exist,
// so the vmcnt(0)+barrier drain per K-iter was fully exposed (MfmaUtil
// 11.6% == pure-MFMA floor / duration). build_lists widened to 1024 thr.
//
// ws layout (bytes):
//   [0,16M)        x_bf16   [8192][1024]     (reused as combined bf16 later)
//   [16M,32M)      weT      [8][1024 d][1024 h] bf16 (transposed)
//   [32M,34M)      woT      [1024 e][1024 d] bf16 (transposed)
//   [34M,66M)      outslot  [8192 tok][2 slot][1024] bf16
//   [66M+..]       counts[8], tok2[8][8192], wlist[8][8192], eidx[16384], ew[16384]

#define TOKENS 8192
#define HDIM   1024
#define DDIM   1024
#define NEXP   8

typedef __bf16 bf16x8 __attribute__((ext_vector_type(8)));
typedef float  f32x4  __attribute__((ext_vector_type(4)));

__device__ __forceinline__ unsigned short f2b(float f) {
  unsigned int u = __builtin_bit_cast(unsigned int, f);
  u = u + 0x7fffu + ((u >> 16) & 1u);   // round-to-nearest-even
  return (unsigned short)(u >> 16);
}
__device__ __forceinline__ float b2f(unsigned short b) {
  unsigned int u = ((unsigned int)b) << 16;
  return __builtin_bit_cast(float, u);
}

// ---------------- weight transpose+convert (we: slices 0..7, wo: slice 8) --

__global__ void transpose_cvt_kernel(const float* __restrict__ we, const float* __restrict__ wo,
                                     unsigned short* __restrict__ weT, unsigned short* __restrict__ woT) {
  __shared__ unsigned short tile[32][33];
  int z = blockIdx.z;
  const float* s;
  unsigned short* d;
  if (z < 8) { s = we + (size_t)z * HDIM * DDIM; d = weT + (size_t)z * HDIM * DDIM; }
  else       { s = wo;                            d = woT; }
  int bx = blockIdx.x * 32;   // src col / dst row
  int by = blockIdx.y * 32;   // src row / dst col
  for (int i = threadIdx.y; i < 32; i += 8)
    tile[i][threadIdx.x] = f2b(s[(size_t)(by + i) * 1024 + bx + threadIdx.x]);
  __syncthreads();
  for (int i = threadIdx.y; i < 32; i += 8)
    d[(size_t)(bx + i) * 1024 + by + threadIdx.x] = tile[threadIdx.x][i];
}

// ---------------- router pass 1: per-token top2 + x->bf16 (no atomics) -----

__global__ void router_compute_kernel(const float* __restrict__ x, const float* __restrict__ wr,
                                      const float* __restrict__ br,
                                      int* __restrict__ eidx, float* __restrict__ ew,
                                      unsigned short* __restrict__ xb) {
  int wave = threadIdx.x >> 6, lane = threadIdx.x & 63;
  int t = blockIdx.x * 4 + wave;
  const float* xp = x + (size_t)t * HDIM;
  unsigned short* xbp = xb + (size_t)t * HDIM;
  float acc[8];
#pragma unroll
  for (int e = 0; e < 8; ++e) acc[e] = 0.f;
#pragma unroll
  for (int h0 = 0; h0 < HDIM; h0 += 256) {
    int h = h0 + lane * 4;
    float4 xv = *(const float4*)&xp[h];
    ushort4 o;
    o.x = f2b(xv.x); o.y = f2b(xv.y); o.z = f2b(xv.z); o.w = f2b(xv.w);
    *(ushort4*)&xbp[h] = o;
    float xq[4] = {xv.x, xv.y, xv.z, xv.w};
#pragma unroll
    for (int q = 0; q < 4; ++q) {
      const float4* wp = (const float4*)&wr[(h + q) * 8];
      float4 w0 = wp[0], w1 = wp[1];
      acc[0] += xq[q] * w0.x; acc[1] += xq[q] * w0.y; acc[2] += xq[q] * w0.z; acc[3] += xq[q] * w0.w;
      acc[4] += xq[q] * w1.x; acc[5] += xq[q] * w1.y; acc[6] += xq[q] * w1.z; acc[7] += xq[q] * w1.w;
    }
  }
#pragma unroll
  for (int off = 32; off; off >>= 1)
#pragma unroll
    for (int e = 0; e < 8; ++e) acc[e] += __shfl_xor(acc[e], off, 64);
  if (lane == 0) {
    float l[8], p[8];
    float m = -1e30f;
#pragma unroll
    for (int e = 0; e < 8; ++e) { l[e] = acc[e] + br[e]; m = fmaxf(m, l[e]); }
    float s = 0.f;
#pragma unroll
    for (int e = 0; e < 8; ++e) { p[e] = __expf(l[e] - m); s += p[e]; }
    int i1 = 0;
#pragma unroll
    for (int e = 1; e < 8; ++e) if (p[e] > p[i1]) i1 = e;   // ties -> lower idx
    int i2 = (i1 == 0) ? 1 : 0;
#pragma unroll
    for (int e = 0; e < 8; ++e) if (e != i1 && p[e] > p[i2]) i2 = e;
    float ps = p[i1] + p[i2];
    eidx[t * 2]     = i1;  ew[t * 2]     = p[i1] / ps;
    eidx[t * 2 + 1] = i2;  ew[t * 2 + 1] = p[i2] / ps;
  }
}

// ---------------- router pass 2: per-expert stream compaction --------------
// 8 blocks x 1024 threads. Deterministic (slot-index order), no atomics.

__global__ __launch_bounds__(1024) void build_lists_kernel(
    const int* __restrict__ eidx, const float* __restrict__ ew,
    int* __restrict__ counts, int* __restrict__ tok2, float* __restrict__ wl) {
  int e = blockIdx.x;
  int tid = threadIdx.x;
  int lane = tid & 63, wv = tid >> 6;    // 16 waves
  __shared__ int wsum[16];
  __shared__ int base;
  if (tid == 0) base = 0;
  __syncthreads();
  for (int c = 0; c < 2 * TOKENS; c += 1024) {
    int i = c + tid;
    bool m = (eidx[i] == e);
    unsigned long long bal = __ballot(m);
    if (lane == 0) wsum[wv] = __popcll(bal);
    __syncthreads();                       // wsum visible
    int wbase = base;
    for (int w = 0; w < wv; ++w) wbase += wsum[w];
    if (m) {
      int pos = wbase + __popcll(bal & ((1ull << lane) - 1ull));
      tok2[e * TOKENS + pos] = i;          // i = token*2 + slot  (outslot row)
      wl[e * TOKENS + pos] = ew[i];
    }
    int total = 0;
#pragma unroll
    for (int w = 0; w < 16; ++w) total += wsum[w];
    __syncthreads();                       // all reads of base done
    if (tid == 0) base += total;
    __syncthreads();                       // base update visible
  }
  if (tid == 0) counts[e] = base;
}

// ---------------- gathered expert GEMM, LDS-free direct-to-register --------
// C-tile 128x128, 4 waves 2x2. Pipeline unit = 32 k-elems (one MFMA K).
// No barriers in K-loop: loads for step+1 issued before MFMAs of step.

__global__ __launch_bounds__(256) void expert_gemm_kernel(
    const unsigned short* __restrict__ xb, const unsigned short* __restrict__ weT,
    const float* __restrict__ b_experts, const int* __restrict__ counts,
    const int* __restrict__ tok2, const float* __restrict__ wlist,
    unsigned short* __restrict__ outslot) {
  int e = blockIdx.z;
  int cnt = counts[e];
  int m0 = blockIdx.y * 128;
  if (m0 >= cnt) return;
  int n0 = blockIdx.x * 128;

  __shared__ int   tokS[128];
  __shared__ float wS[128];
  int tid = threadIdx.x;
  if (tid < 128) {
    int r = m0 + tid;
    tokS[tid] = (r < cnt) ? tok2[e * TOKENS + r] : 0;
    wS[tid]   = (r < cnt) ? wlist[e * TOKENS + r] : 0.f;
  }
  __syncthreads();

  int wave = tid >> 6, lane = tid & 63;
  int wm = wave & 1, wn = wave >> 1;
  int quad = lane >> 4, lr = lane & 15;

  const unsigned short* aptr[4];
  const unsigned short* bptr[4];
  const unsigned short* wbase = weT + (size_t)e * (HDIM * DDIM);
#pragma unroll
  for (int i = 0; i < 4; ++i) {
    int tok = tokS[wm * 64 + i * 16 + lr] >> 1;
    aptr[i] = xb + (size_t)tok * HDIM + quad * 8;
    bptr[i] = wbase + (size_t)(n0 + wn * 64 + i * 16 + lr) * HDIM + quad * 8;
  }

  f32x4 zero = {0.f, 0.f, 0.f, 0.f};
  f32x4 acc[4][4];
#pragma unroll
  for (int i = 0; i < 4; ++i)
#pragma unroll
    for (int j = 0; j < 4; ++j) acc[i][j] = zero;

  bf16x8 a_cur[4], b_cur[4];
#pragma unroll
  for (int i = 0; i < 4; ++i) {
    a_cur[i] = *(const bf16x8*)(aptr[i]);
    b_cur[i] = *(const bf16x8*)(bptr[i]);
  }
#pragma unroll 4
  for (int step = 0; step < 31; ++step) {
    bf16x8 a_nxt[4], b_nxt[4];
    int off = (step + 1) * 32;
#pragma unroll
    for (int i = 0; i < 4; ++i) {
      a_nxt[i] = *(const bf16x8*)(aptr[i] + off);
      b_nxt[i] = *(const bf16x8*)(bptr[i] + off);
    }
#pragma unroll
    for (int i = 0; i < 4; ++i)
#pragma unroll
      for (int j = 0; j < 4; ++j)
        acc[i][j] = __builtin_amdgcn_mfma_f32_16x16x32_bf16(a_cur[i], b_cur[j], acc[i][j], 0, 0, 0);
#pragma unroll
    for (int i = 0; i < 4; ++i) { a_cur[i] = a_nxt[i]; b_cur[i] = b_nxt[i]; }
  }
#pragma unroll
  for (int i = 0; i < 4; ++i)
#pragma unroll
    for (int j = 0; j < 4; ++j)
      acc[i][j] = __builtin_amdgcn_mfma_f32_16x16x32_bf16(a_cur[i], b_cur[j], acc[i][j], 0, 0, 0);

#pragma unroll
  for (int j = 0; j < 4; ++j) {
    int col = n0 + wn * 64 + j * 16 + lr;
    float bias = b_experts[e * DDIM + col];
#pragma unroll
    for (int i = 0; i < 4; ++i) {
      int rbase = wm * 64 + i * 16 + quad * 4;
#pragma unroll
      for (int r = 0; r < 4; ++r) {
        int row = rbase + r;
        if (m0 + row < cnt) {
          float h = acc[i][j][r] + bias;
          float z = 0.7978845608f * (h + 0.044715f * h * h * h);
          float t = 1.f - 2.f / (__expf(2.f * z) + 1.f);   // tanh(z), saturates safely
          float g = 0.5f * h * (1.f + t);
          outslot[(size_t)tokS[row] * DDIM + col] = f2b(g * wS[row]);
        }
      }
    }
  }
}

// ---------------- combine the two slots -> bf16 combined ----------------

__global__ void combine_kernel(const ushort4* __restrict__ outslot, ushort4* __restrict__ comb) {
  int i = blockIdx.x * 256 + threadIdx.x;  // TOKENS*DDIM/4 threads
  int t = i >> 8, d4 = i & 255;
  ushort4 a = outslot[t * 512 + d4];
  ushort4 b = outslot[t * 512 + 256 + d4];
  ushort4 o;
  o.x = f2b(b2f(a.x) + b2f(b.x));
  o.y = f2b(b2f(a.y) + b2f(b.y));
  o.z = f2b(b2f(a.z) + b2f(b.z));
  o.w = f2b(b2f(a.w) + b2f(b.w));
  comb[i] = o;
}

// ---------------- output projection GEMM, LDS-free (fp32 out) -------------

__global__ __launch_bounds__(256) void out_gemm_kernel(
    const unsigned short* __restrict__ Abf, const unsigned short* __restrict__ BT,
    const float* __restrict__ bias, float* __restrict__ out) {
  int m0 = blockIdx.y * 128, n0 = blockIdx.x * 128;
  int tid = threadIdx.x, wave = tid >> 6, lane = tid & 63;
  int wm = wave & 1, wn = wave >> 1;
  int quad = lane >> 4, lr = lane & 15;

  const unsigned short* aptr[4];
  const unsigned short* bptr[4];
#pragma unroll
  for (int i = 0; i < 4; ++i) {
    aptr[i] = Abf + (size_t)(m0 + wm * 64 + i * 16 + lr) * DDIM + quad * 8;
    bptr[i] = BT + (size_t)(n0 + wn * 64 + i * 16 + lr) * DDIM + quad * 8;
  }

  f32x4 zero = {0.f, 0.f, 0.f, 0.f};
  f32x4 acc[4][4];
#pragma unroll
  for (int i = 0; i < 4; ++i)
#pragma unroll
    for (int j = 0; j < 4; ++j) acc[i][j] = zero;

  bf16x8 a_cur[4], b_cur[4];
#pragma unroll
  for (int i = 0; i < 4; ++i) {
    a_cur[i] = *(const bf16x8*)(aptr[i]);
    b_cur[i] = *(const bf16x8*)(bptr[i]);
  }
#pragma unroll 4
  for (int step = 0; step < 31; ++step) {
    bf16x8 a_nxt[4], b_nxt[4];
    int off = (step + 1) * 32;
#pragma unroll
    for (int i = 0; i < 4; ++i) {
      a_nxt[i] = *(const bf16x8*)(aptr[i] + off);
      b_nxt[i] = *(const bf16x8*)(bptr[i] + off);
    }
#pragma unroll
    for (int i = 0; i < 4; ++i)
#pragma unroll
      for (int j = 0; j < 4; ++j)
        acc[i][j] = __builtin_amdgcn_mfma_f32_16x16x32_bf16(a_cur[i], b_cur[j], acc[i][j], 0, 0, 0);
#pragma unroll
    for (int i = 0; i < 4; ++i) { a_cur[i] = a_nxt[i]; b_cur[i] = b_nxt[i]; }
  }
#pragma unroll
  for (int i = 0; i < 4; ++i)
#pragma unroll
    for (int j = 0; j < 4; ++j)
      acc[i][j] = __builtin_amdgcn_mfma_f32_16x16x32_bf16(a_cur[i], b_cur[j], acc[i][j], 0, 0, 0);

#pragma unroll
  for (int j = 0; j < 4; ++j) {
    int col = n0 + wn * 64 + j * 16 + lr;
    float bs = bias[col];
#pragma unroll
    for (int i = 0; i < 4; ++i) {
      int rbase = wm * 64 + i * 16 + quad * 4;
#pragma unroll
      for (int r = 0; r < 4; ++r)
        out[(size_t)(m0 + rbase + r) * DDIM + col] = acc[i][j][r] + bs;
    }
  }
}

// ---------------- launch ----------------

extern "C" void kernel_launch(void* const* d_in, const int* in_sizes, int n_in,
                              void* d_out, int out_size, void* d_ws, size_t ws_size,
                              hipStream_t stream) {
  const float* x  = (const float*)d_in[0];
  const float* wr = (const float*)d_in[1];
  const float* br = (const float*)d_in[2];
  const float* we = (const float*)d_in[3];
  const float* be = (const float*)d_in[4];
  const float* wo = (const float*)d_in[5];
  const float* bo = (const float*)d_in[6];
  float* out = (float*)d_out;

  char* ws = (char*)d_ws;
  unsigned short* xb      = (unsigned short*)(ws);                  // 16 MB
  unsigned short* weT     = (unsigned short*)(ws + 16777216);       // 16 MB
  unsigned short* woT     = (unsigned short*)(ws + 33554432);       //  2 MB
  unsigned short* outslot = (unsigned short*)(ws + 35651584);       // 32 MB
  int*            counts  = (int*)           (ws + 69206016);       // 256 B
  int*            tok2    = (int*)           (ws + 69206272);       // 256 KB
  float*          wlist   = (float*)         (ws + 69468416);       // 256 KB
  int*            eidx    = (int*)           (ws + 69730560);       // 64 KB
  float*          ew      = (float*)         (ws + 69796096);       // 64 KB
  unsigned short* comb    = xb;   // alias: xb dead after expert_gemm

  router_compute_kernel<<<2048, 256, 0, stream>>>(x, wr, br, eidx, ew, xb);
  transpose_cvt_kernel<<<dim3(32, 32, 9), dim3(32, 8), 0, stream>>>(we, wo, weT, woT);
  build_lists_kernel<<<8, 1024, 0, stream>>>(eidx, ew, counts, tok2, wlist);
  expert_gemm_kernel<<<dim3(8, 64, 8), 256, 0, stream>>>(xb, weT, be, counts, tok2, wlist, outslot);
  combine_kernel<<<8192, 256, 0, stream>>>((const ushort4*)outslot, (ushort4*)comb);
  out_gemm_kernel<<<dim3(8, 64), 256, 0, stream>>>(comb, woT, bo, out);
}

// Round 4
// 286.770 us; speedup vs baseline: 1.5487x; 1.5487x over previous
//
#include <hip/hip_runtime.h>

// DynamicExpertGating: routed MoE on MI355X (gfx950)
//   tokens T=8192 (B4 x S2048), H=1024, D=1024, E=8, top-2
// R4: revert GEMMs to LDS staging (R3's LDS-free direct-register loop was
// latency-bound: 16 scattered segments/load, 1-deep pipeline -> 225us).
// New: BK=32 + prefetch double-buffer (vmcnt drain covered by MFMA step)
// + XCD swizzle (one expert per XCD -> B 2MB + A-tile in local L2).
//
// ws layout (bytes):
//   [0,16M)        x_bf16   [8192][1024]     (reused as combined bf16 later)
//   [16M,32M)      weT      [8][1024 d][1024 h] bf16 (transposed)
//   [32M,34M)      woT      [1024 e][1024 d] bf16 (transposed)
//   [34M,66M)      outslot  [8192 tok][2 slot][1024] bf16
//   [66M+..]       counts[8], tok2[8][8192], wlist[8][8192], eidx[16384], ew[16384]

#define TOKENS 8192
#define HDIM   1024
#define DDIM   1024
#define NEXP   8

typedef __bf16 bf16x8 __attribute__((ext_vector_type(8)));
typedef float  f32x4  __attribute__((ext_vector_type(4)));

__device__ __forceinline__ unsigned short f2b(float f) {
  unsigned int u = __builtin_bit_cast(unsigned int, f);
  u = u + 0x7fffu + ((u >> 16) & 1u);   // round-to-nearest-even
  return (unsigned short)(u >> 16);
}
__device__ __forceinline__ float b2f(unsigned short b) {
  unsigned int u = ((unsigned int)b) << 16;
  return __builtin_bit_cast(float, u);
}

__device__ __forceinline__ void gld_lds16(const void* g, void* l) {
  __builtin_amdgcn_global_load_lds(
      (__attribute__((address_space(1))) void*)(g),
      (__attribute__((address_space(3))) void*)(l),
      16, 0, 0);
}

// ---------------- weight transpose+convert (we: slices 0..7, wo: slice 8) --

__global__ void transpose_cvt_kernel(const float* __restrict__ we, const float* __restrict__ wo,
                                     unsigned short* __restrict__ weT, unsigned short* __restrict__ woT) {
  __shared__ unsigned short tile[32][33];
  int z = blockIdx.z;
  const float* s;
  unsigned short* d;
  if (z < 8) { s = we + (size_t)z * HDIM * DDIM; d = weT + (size_t)z * HDIM * DDIM; }
  else       { s = wo;                            d = woT; }
  int bx = blockIdx.x * 32;   // src col / dst row
  int by = blockIdx.y * 32;   // src row / dst col
  for (int i = threadIdx.y; i < 32; i += 8)
    tile[i][threadIdx.x] = f2b(s[(size_t)(by + i) * 1024 + bx + threadIdx.x]);
  __syncthreads();
  for (int i = threadIdx.y; i < 32; i += 8)
    d[(size_t)(bx + i) * 1024 + by + threadIdx.x] = tile[threadIdx.x][i];
}

// ---------------- router pass 1: per-token top2 + x->bf16 (no atomics) -----

__global__ void router_compute_kernel(const float* __restrict__ x, const float* __restrict__ wr,
                                      const float* __restrict__ br,
                                      int* __restrict__ eidx, float* __restrict__ ew,
                                      unsigned short* __restrict__ xb) {
  int wave = threadIdx.x >> 6, lane = threadIdx.x & 63;
  int t = blockIdx.x * 4 + wave;
  const float* xp = x + (size_t)t * HDIM;
  unsigned short* xbp = xb + (size_t)t * HDIM;
  float acc[8];
#pragma unroll
  for (int e = 0; e < 8; ++e) acc[e] = 0.f;
#pragma unroll
  for (int h0 = 0; h0 < HDIM; h0 += 256) {
    int h = h0 + lane * 4;
    float4 xv = *(const float4*)&xp[h];
    ushort4 o;
    o.x = f2b(xv.x); o.y = f2b(xv.y); o.z = f2b(xv.z); o.w = f2b(xv.w);
    *(ushort4*)&xbp[h] = o;
    float xq[4] = {xv.x, xv.y, xv.z, xv.w};
#pragma unroll
    for (int q = 0; q < 4; ++q) {
      const float4* wp = (const float4*)&wr[(h + q) * 8];
      float4 w0 = wp[0], w1 = wp[1];
      acc[0] += xq[q] * w0.x; acc[1] += xq[q] * w0.y; acc[2] += xq[q] * w0.z; acc[3] += xq[q] * w0.w;
      acc[4] += xq[q] * w1.x; acc[5] += xq[q] * w1.y; acc[6] += xq[q] * w1.z; acc[7] += xq[q] * w1.w;
    }
  }
#pragma unroll
  for (int off = 32; off; off >>= 1)
#pragma unroll
    for (int e = 0; e < 8; ++e) acc[e] += __shfl_xor(acc[e], off, 64);
  if (lane == 0) {
    float l[8], p[8];
    float m = -1e30f;
#pragma unroll
    for (int e = 0; e < 8; ++e) { l[e] = acc[e] + br[e]; m = fmaxf(m, l[e]); }
    float s = 0.f;
#pragma unroll
    for (int e = 0; e < 8; ++e) { p[e] = __expf(l[e] - m); s += p[e]; }
    int i1 = 0;
#pragma unroll
    for (int e = 1; e < 8; ++e) if (p[e] > p[i1]) i1 = e;   // ties -> lower idx
    int i2 = (i1 == 0) ? 1 : 0;
#pragma unroll
    for (int e = 0; e < 8; ++e) if (e != i1 && p[e] > p[i2]) i2 = e;
    float ps = p[i1] + p[i2];
    eidx[t * 2]     = i1;  ew[t * 2]     = p[i1] / ps;
    eidx[t * 2 + 1] = i2;  ew[t * 2 + 1] = p[i2] / ps;
  }
}

// ---------------- router pass 2: per-expert stream compaction --------------
// 8 blocks x 1024 threads. Deterministic (slot-index order), no atomics.

__global__ __launch_bounds__(1024) void build_lists_kernel(
    const int* __restrict__ eidx, const float* __restrict__ ew,
    int* __restrict__ counts, int* __restrict__ tok2, float* __restrict__ wl) {
  int e = blockIdx.x;
  int tid = threadIdx.x;
  int lane = tid & 63, wv = tid >> 6;    // 16 waves
  __shared__ int wsum[16];
  __shared__ int base;
  if (tid == 0) base = 0;
  __syncthreads();
  for (int c = 0; c < 2 * TOKENS; c += 1024) {
    int i = c + tid;
    bool m = (eidx[i] == e);
    unsigned long long bal = __ballot(m);
    if (lane == 0) wsum[wv] = __popcll(bal);
    __syncthreads();                       // wsum visible
    int wbase = base;
    for (int w = 0; w < wv; ++w) wbase += wsum[w];
    if (m) {
      int pos = wbase + __popcll(bal & ((1ull << lane) - 1ull));
      tok2[e * TOKENS + pos] = i;          // i = token*2 + slot  (outslot row)
      wl[e * TOKENS + pos] = ew[i];
    }
    int total = 0;
#pragma unroll
    for (int w = 0; w < 16; ++w) total += wsum[w];
    __syncthreads();                       // all reads of base done
    if (tid == 0) base += total;
    __syncthreads();                       // base update visible
  }
  if (tid == 0) counts[e] = base;
}

// ---------------- gathered expert GEMM + gelu*gate epilogue ----------------
// C-tile 128x128, BK=32, double-buffered LDS prefetch, 4 waves 2x2.
// XCD swizzle: one expert per XCD (B slab 2MB + A-tile L2-resident).

__global__ __launch_bounds__(256, 4) void expert_gemm_kernel(
    const unsigned short* __restrict__ xb, const unsigned short* __restrict__ weT,
    const float* __restrict__ b_experts, const int* __restrict__ counts,
    const int* __restrict__ tok2, const float* __restrict__ wlist,
    unsigned short* __restrict__ outslot) {
  int b = blockIdx.x;
  int id = (b >> 3) + (b & 7) * 512;      // XCD k <- expert k's 512 tiles
  int e = id >> 9;
  int rem = id & 511;
  int m0 = (rem >> 3) << 7;               // 64 m-tiles, n fastest
  int n0 = (rem & 7) << 7;
  int cnt = counts[e];
  if (m0 >= cnt) return;

  __shared__ unsigned short As[2][128 * 32];   // [m][k]
  __shared__ unsigned short Bs[2][128 * 32];   // [n][k]
  __shared__ int   tokS[128];
  __shared__ float wS[128];

  int tid = threadIdx.x;
  if (tid < 128) {
    int r = m0 + tid;
    tokS[tid] = (r < cnt) ? tok2[e * TOKENS + r] : 0;
    wS[tid]   = (r < cnt) ? wlist[e * TOKENS + r] : 0.f;
  }
  __syncthreads();

  int wave = tid >> 6, lane = tid & 63;
  int subr = lane >> 2, koff = (lane & 3) * 8;

  const unsigned short* wbase = weT + (size_t)e * (HDIM * DDIM);
  const unsigned short* asrc[2];
  const unsigned short* bsrc[2];
  unsigned short* adst[2][2];
  unsigned short* bdst[2][2];
#pragma unroll
  for (int i = 0; i < 2; ++i) {
    int row = i * 64 + wave * 16 + subr;
    asrc[i] = xb + (size_t)(tokS[row] >> 1) * HDIM + koff;
    bsrc[i] = wbase + (size_t)(n0 + row) * HDIM + koff;
#pragma unroll
    for (int bb = 0; bb < 2; ++bb) {
      adst[bb][i] = &As[bb][i * 2048 + wave * 512];
      bdst[bb][i] = &Bs[bb][i * 2048 + wave * 512];
    }
  }

  int wm = wave & 1, wn = wave >> 1;
  int quad = lane >> 4, lr = lane & 15;

  f32x4 zero = {0.f, 0.f, 0.f, 0.f};
  f32x4 acc[4][4];
#pragma unroll
  for (int i = 0; i < 4; ++i)
#pragma unroll
    for (int j = 0; j < 4; ++j) acc[i][j] = zero;

  // prologue: stage k-step 0 into buffer 0
#pragma unroll
  for (int i = 0; i < 2; ++i) {
    gld_lds16(asrc[i], adst[0][i]);
    gld_lds16(bsrc[i], bdst[0][i]);
  }

#pragma unroll 2
  for (int kk = 0; kk < 32; ++kk) {
    __syncthreads();                 // drains vmcnt -> buffer kk&1 valid
    if (kk < 31) {                   // prefetch next step into other buffer
      int off = (kk + 1) * 32;
      int nb = (kk + 1) & 1;
#pragma unroll
      for (int i = 0; i < 2; ++i) {
        gld_lds16(asrc[i] + off, adst[nb][i]);
        gld_lds16(bsrc[i] + off, bdst[nb][i]);
      }
    }
    int cb = kk & 1;
    bf16x8 af[4], bfr[4];
#pragma unroll
    for (int i = 0; i < 4; ++i)
      af[i] = *(const bf16x8*)&As[cb][(wm * 64 + i * 16 + lr) * 32 + quad * 8];
#pragma unroll
    for (int j = 0; j < 4; ++j)
      bfr[j] = *(const bf16x8*)&Bs[cb][(wn * 64 + j * 16 + lr) * 32 + quad * 8];
#pragma unroll
    for (int i = 0; i < 4; ++i)
#pragma unroll
      for (int j = 0; j < 4; ++j)
        acc[i][j] = __builtin_amdgcn_mfma_f32_16x16x32_bf16(af[i], bfr[j], acc[i][j], 0, 0, 0);
  }

#pragma unroll
  for (int j = 0; j < 4; ++j) {
    int col = n0 + wn * 64 + j * 16 + lr;
    float bias = b_experts[e * DDIM + col];
#pragma unroll
    for (int i = 0; i < 4; ++i) {
      int rbase = wm * 64 + i * 16 + quad * 4;
#pragma unroll
      for (int r = 0; r < 4; ++r) {
        int row = rbase + r;
        if (m0 + row < cnt) {
          float h = acc[i][j][r] + bias;
          float z = 0.7978845608f * (h + 0.044715f * h * h * h);
          float t = 1.f - 2.f / (__expf(2.f * z) + 1.f);   // tanh(z), saturates safely
          float g = 0.5f * h * (1.f + t);
          outslot[(size_t)tokS[row] * DDIM + col] = f2b(g * wS[row]);
        }
      }
    }
  }
}

// ---------------- combine the two slots -> bf16 combined ----------------

__global__ void combine_kernel(const ushort4* __restrict__ outslot, ushort4* __restrict__ comb) {
  int i = blockIdx.x * 256 + threadIdx.x;  // TOKENS*DDIM/4 threads
  int t = i >> 8, d4 = i & 255;
  ushort4 a = outslot[t * 512 + d4];
  ushort4 b = outslot[t * 512 + 256 + d4];
  ushort4 o;
  o.x = f2b(b2f(a.x) + b2f(b.x));
  o.y = f2b(b2f(a.y) + b2f(b.y));
  o.z = f2b(b2f(a.z) + b2f(b.z));
  o.w = f2b(b2f(a.w) + b2f(b.w));
  comb[i] = o;
}

// ---------------- output projection GEMM (fp32 out) ----------------
// Same structure: BK=32 dbuf prefetch, XCD swizzle (n-slab per XCD).

__global__ __launch_bounds__(256, 4) void out_gemm_kernel(
    const unsigned short* __restrict__ Abf, const unsigned short* __restrict__ BT,
    const float* __restrict__ bias, float* __restrict__ out) {
  int b = blockIdx.x;
  int id = (b >> 3) + (b & 7) * 64;       // XCD k <- n-tile k's 64 m-tiles
  int n0 = (id >> 6) << 7;
  int m0 = (id & 63) << 7;

  __shared__ unsigned short As[2][128 * 32];
  __shared__ unsigned short Bs[2][128 * 32];
  int tid = threadIdx.x, wave = tid >> 6, lane = tid & 63;
  int subr = lane >> 2, koff = (lane & 3) * 8;

  const unsigned short* asrc[2];
  const unsigned short* bsrc[2];
  unsigned short* adst[2][2];
  unsigned short* bdst[2][2];
#pragma unroll
  for (int i = 0; i < 2; ++i) {
    int row = i * 64 + wave * 16 + subr;
    asrc[i] = Abf + (size_t)(m0 + row) * DDIM + koff;
    bsrc[i] = BT + (size_t)(n0 + row) * DDIM + koff;
#pragma unroll
    for (int bb = 0; bb < 2; ++bb) {
      adst[bb][i] = &As[bb][i * 2048 + wave * 512];
      bdst[bb][i] = &Bs[bb][i * 2048 + wave * 512];
    }
  }

  int wm = wave & 1, wn = wave >> 1;
  int quad = lane >> 4, lr = lane & 15;

  f32x4 zero = {0.f, 0.f, 0.f, 0.f};
  f32x4 acc[4][4];
#pragma unroll
  for (int i = 0; i < 4; ++i)
#pragma unroll
    for (int j = 0; j < 4; ++j) acc[i][j] = zero;

#pragma unroll
  for (int i = 0; i < 2; ++i) {
    gld_lds16(asrc[i], adst[0][i]);
    gld_lds16(bsrc[i], bdst[0][i]);
  }

#pragma unroll 2
  for (int kk = 0; kk < 32; ++kk) {
    __syncthreads();
    if (kk < 31) {
      int off = (kk + 1) * 32;
      int nb = (kk + 1) & 1;
#pragma unroll
      for (int i = 0; i < 2; ++i) {
        gld_lds16(asrc[i] + off, adst[nb][i]);
        gld_lds16(bsrc[i] + off, bdst[nb][i]);
      }
    }
    int cb = kk & 1;
    bf16x8 af[4], bfr[4];
#pragma unroll
    for (int i = 0; i < 4; ++i)
      af[i] = *(const bf16x8*)&As[cb][(wm * 64 + i * 16 + lr) * 32 + quad * 8];
#pragma unroll
    for (int j = 0; j < 4; ++j)
      bfr[j] = *(const bf16x8*)&Bs[cb][(wn * 64 + j * 16 + lr) * 32 + quad * 8];
#pragma unroll
    for (int i = 0; i < 4; ++i)
#pragma unroll
      for (int j = 0; j < 4; ++j)
        acc[i][j] = __builtin_amdgcn_mfma_f32_16x16x32_bf16(af[i], bfr[j], acc[i][j], 0, 0, 0);
  }

#pragma unroll
  for (int j = 0; j < 4; ++j) {
    int col = n0 + wn * 64 + j * 16 + lr;
    float bs = bias[col];
#pragma unroll
    for (int i = 0; i < 4; ++i) {
      int rbase = wm * 64 + i * 16 + quad * 4;
#pragma unroll
      for (int r = 0; r < 4; ++r)
        out[(size_t)(m0 + rbase + r) * DDIM + col] = acc[i][j][r] + bs;
    }
  }
}

// ---------------- launch ----------------

extern "C" void kernel_launch(void* const* d_in, const int* in_sizes, int n_in,
                              void* d_out, int out_size, void* d_ws, size_t ws_size,
                              hipStream_t stream) {
  const float* x  = (const float*)d_in[0];
  const float* wr = (const float*)d_in[1];
  const float* br = (const float*)d_in[2];
  const float* we = (const float*)d_in[3];
  const float* be = (const float*)d_in[4];
  const float* wo = (const float*)d_in[5];
  const float* bo = (const float*)d_in[6];
  float* out = (float*)d_out;

  char* ws = (char*)d_ws;
  unsigned short* xb      = (unsigned short*)(ws);                  // 16 MB
  unsigned short* weT     = (unsigned short*)(ws + 16777216);       // 16 MB
  unsigned short* woT     = (unsigned short*)(ws + 33554432);       //  2 MB
  unsigned short* outslot = (unsigned short*)(ws + 35651584);       // 32 MB
  int*            counts  = (int*)           (ws + 69206016);       // 256 B
  int*            tok2    = (int*)           (ws + 69206272);       // 256 KB
  float*          wlist   = (float*)         (ws + 69468416);       // 256 KB
  int*            eidx    = (int*)           (ws + 69730560);       // 64 KB
  float*          ew      = (float*)         (ws + 69796096);       // 64 KB
  unsigned short* comb    = xb;   // alias: xb dead after expert_gemm

  router_compute_kernel<<<2048, 256, 0, stream>>>(x, wr, br, eidx, ew, xb);
  transpose_cvt_kernel<<<dim3(32, 32, 9), dim3(32, 8), 0, stream>>>(we, wo, weT, woT);
  build_lists_kernel<<<8, 1024, 0, stream>>>(eidx, ew, counts, tok2, wlist);
  expert_gemm_kernel<<<4096, 256, 0, stream>>>(xb, weT, be, counts, tok2, wlist, outslot);
  combine_kernel<<<8192, 256, 0, stream>>>((const ushort4*)outslot, (ushort4*)comb);
  out_gemm_kernel<<<512, 256, 0, stream>>>(comb, woT, bo, out);
}